// Round 1
// baseline (2865.134 us; speedup 1.0000x reference)
//
#include <hip/hip_runtime.h>
#include <math.h>

#define Bn 128
#define Tn 512
#define Dn 32
#define Hn 128
#define Gn 512   // 4*H
#define Ln 3

// ---------------------------------------------------------------------------
// GEMM: pre[M, 512] = A_chunk[M, K] * W[512, K]^T + (b_ih + b_hh)
// A rows map to (b, t) with per-batch stride rowStrideB (= T*K), chunk offset t0.
// Tile 128x128, 256 threads, 8x8 outputs/thread, K-chunks of 8.
// ---------------------------------------------------------------------------
__global__ __launch_bounds__(256) void gemm_pre(
    const float* __restrict__ A, int K, int rowStrideB, int t0, int tlog,
    const float* __restrict__ W,
    const float* __restrict__ bi, const float* __restrict__ bh,
    float* __restrict__ C)
{
    __shared__ __align__(16) float As[8][128];
    __shared__ __align__(16) float Bs[8][128];
    const int tid  = threadIdx.x;
    const int row0 = blockIdx.x * 128;
    const int col0 = blockIdx.y * 128;
    const int ty = tid >> 4, tx = tid & 15;
    const int lr = tid >> 1, lk = (tid & 1) * 4;
    const int tmask = (1 << tlog) - 1;

    float acc[8][8];
    #pragma unroll
    for (int i = 0; i < 8; i++)
        #pragma unroll
        for (int j = 0; j < 8; j++) acc[i][j] = 0.f;

    for (int k0 = 0; k0 < K; k0 += 8) {
        // A tile (gap-aware rows)
        {
            int rg = row0 + lr;
            int b_idx = rg >> tlog;
            int tt = rg & tmask;
            const float* ap = A + (size_t)b_idx * rowStrideB +
                              (size_t)(t0 + tt) * K + (k0 + lk);
            float4 av = *(const float4*)ap;
            As[lk + 0][lr] = av.x; As[lk + 1][lr] = av.y;
            As[lk + 2][lr] = av.z; As[lk + 3][lr] = av.w;
            const float* wp = W + (size_t)(col0 + lr) * K + (k0 + lk);
            float4 wv = *(const float4*)wp;
            Bs[lk + 0][lr] = wv.x; Bs[lk + 1][lr] = wv.y;
            Bs[lk + 2][lr] = wv.z; Bs[lk + 3][lr] = wv.w;
        }
        __syncthreads();
        #pragma unroll
        for (int kk = 0; kk < 8; kk++) {
            float4 a0 = *(const float4*)&As[kk][ty * 8];
            float4 a1 = *(const float4*)&As[kk][ty * 8 + 4];
            float4 b0 = *(const float4*)&Bs[kk][tx * 8];
            float4 b1v = *(const float4*)&Bs[kk][tx * 8 + 4];
            float av[8] = {a0.x, a0.y, a0.z, a0.w, a1.x, a1.y, a1.z, a1.w};
            float bv[8] = {b0.x, b0.y, b0.z, b0.w, b1v.x, b1v.y, b1v.z, b1v.w};
            #pragma unroll
            for (int i = 0; i < 8; i++)
                #pragma unroll
                for (int j = 0; j < 8; j++) acc[i][j] += av[i] * bv[j];
        }
        __syncthreads();
    }
    #pragma unroll
    for (int i = 0; i < 8; i++) {
        int r = row0 + ty * 8 + i;
        #pragma unroll
        for (int j = 0; j < 8; j += 4) {
            int g = col0 + tx * 8 + j;
            float4 o;
            o.x = acc[i][j + 0] + bi[g + 0] + bh[g + 0];
            o.y = acc[i][j + 1] + bi[g + 1] + bh[g + 1];
            o.z = acc[i][j + 2] + bi[g + 2] + bh[g + 2];
            o.w = acc[i][j + 3] + bi[g + 3] + bh[g + 3];
            *(float4*)&C[(size_t)r * Gn + g] = o;
        }
    }
}

// ---------------------------------------------------------------------------
// LSTM scan over a chunk of TCH timesteps. One block per batch item,
// 512 threads = one per gate. w_hh row in registers; h/c in LDS.
// PyTorch gate order: i [0,128) f [128,256) g [256,384) o [384,512).
// ---------------------------------------------------------------------------
__global__ __launch_bounds__(512) void lstm_scan(
    const float* __restrict__ pre,     // [B*TCH, 512]
    const float* __restrict__ w_hh,    // [512, 128] (this layer)
    float* __restrict__ hs,            // [B, T, H] layer output
    float* __restrict__ h_state, float* __restrict__ c_state,
    int t0, int TCH, int first)
{
    const int b = blockIdx.x;
    const int g = threadIdx.x;
    __shared__ __align__(16) float h_sh[Hn];
    __shared__ __align__(16) float c_sh[Hn];
    __shared__ __align__(16) float gates[Gn];

    float4 w[32];
    const float4* wp = (const float4*)(w_hh + (size_t)g * Hn);
    #pragma unroll
    for (int k = 0; k < 32; k++) w[k] = wp[k];

    if (g < Hn) {
        h_sh[g] = first ? 0.f : h_state[b * Hn + g];
        c_sh[g] = first ? 0.f : c_state[b * Hn + g];
    }
    __syncthreads();

    const float* preb = pre + (size_t)b * TCH * Gn;
    float* hsb = hs + (size_t)b * Tn * Hn + (size_t)t0 * Hn;

    for (int t = 0; t < TCH; t++) {
        float acc = preb[(size_t)t * Gn + g];
        const float4* h4 = (const float4*)h_sh;
        #pragma unroll
        for (int k = 0; k < 32; k++) {
            float4 hv = h4[k];
            acc += w[k].x * hv.x + w[k].y * hv.y + w[k].z * hv.z + w[k].w * hv.w;
        }
        float act;
        if (g < 256)      act = 1.f / (1.f + __expf(-acc));   // i, f
        else if (g < 384) act = tanhf(acc);                    // g
        else              act = 1.f / (1.f + __expf(-acc));   // o
        gates[g] = act;
        __syncthreads();
        if (g < Hn) {
            float iv = gates[g], fv = gates[Hn + g];
            float gv = gates[2 * Hn + g], ov = gates[3 * Hn + g];
            float c = fv * c_sh[g] + iv * gv;
            float h = ov * tanhf(c);
            c_sh[g] = c; h_sh[g] = h;
            hsb[(size_t)t * Hn + g] = h;
        }
        __syncthreads();
    }
    if (g < Hn) {
        h_state[b * Hn + g] = h_sh[g];
        c_state[b * Hn + g] = c_sh[g];
    }
}

// ---------------------------------------------------------------------------
// Attention pooling + MLP head. One block per batch item, 256 threads.
// ---------------------------------------------------------------------------
__global__ __launch_bounds__(256) void head_kernel(
    const float* __restrict__ hs,      // [B, T, H] (layer 2 output)
    const float* __restrict__ w_attn, const float* __restrict__ b_attn,
    const float* __restrict__ w1, const float* __restrict__ b1,
    const float* __restrict__ w2, const float* __restrict__ b2,
    float* __restrict__ out)
{
    const int b = blockIdx.x;
    const int tid = threadIdx.x;
    __shared__ __align__(16) float wa_sh[Hn];
    __shared__ __align__(16) float sc[Tn];
    __shared__ __align__(16) float red[256];
    __shared__ __align__(16) float ctx_sh[Hn];
    __shared__ __align__(16) float h1_sh[64];

    if (tid < Hn) wa_sh[tid] = w_attn[tid];
    __syncthreads();

    const float* hb = hs + (size_t)b * Tn * Hn;

    // scores over time
    for (int t = tid; t < Tn; t += 256) {
        const float4* hv = (const float4*)(hb + (size_t)t * Hn);
        const float4* wv = (const float4*)wa_sh;
        float s = 0.f;
        #pragma unroll
        for (int k = 0; k < 32; k++) {
            float4 h4 = hv[k], w4 = wv[k];
            s += h4.x * w4.x + h4.y * w4.y + h4.z * w4.z + h4.w * w4.w;
        }
        sc[t] = s + b_attn[0];
    }
    __syncthreads();

    // softmax over T
    float m = fmaxf(sc[tid], sc[tid + 256]);
    red[tid] = m; __syncthreads();
    for (int s_ = 128; s_ > 0; s_ >>= 1) {
        if (tid < s_) red[tid] = fmaxf(red[tid], red[tid + s_]);
        __syncthreads();
    }
    float mx = red[0];
    __syncthreads();
    float e0 = __expf(sc[tid] - mx), e1 = __expf(sc[tid + 256] - mx);
    sc[tid] = e0; sc[tid + 256] = e1;
    red[tid] = e0 + e1; __syncthreads();
    for (int s_ = 128; s_ > 0; s_ >>= 1) {
        if (tid < s_) red[tid] += red[tid + s_];
        __syncthreads();
    }
    float inv = 1.f / red[0];
    __syncthreads();

    // ctx[j] = sum_t attn[t] * h[t][j]
    {
        int j = tid & 127, half = tid >> 7;
        float a = 0.f;
        for (int t = half * 256; t < half * 256 + 256; t++)
            a += sc[t] * hb[(size_t)t * Hn + j];
        red[tid] = a;
        __syncthreads();
        if (tid < Hn) ctx_sh[tid] = (red[tid] + red[tid + Hn]) * inv;
        __syncthreads();
    }

    // h1 = relu(ctx @ w1^T + b1)
    if (tid < 64) {
        const float4* wv = (const float4*)(w1 + (size_t)tid * Hn);
        const float4* cv = (const float4*)ctx_sh;
        float s = 0.f;
        #pragma unroll
        for (int k = 0; k < 32; k++) {
            float4 a = wv[k], c = cv[k];
            s += a.x * c.x + a.y * c.y + a.z * c.z + a.w * c.w;
        }
        h1_sh[tid] = fmaxf(s + b1[tid], 0.f);
    }
    __syncthreads();

    // out = h1 @ w2^T + b2
    if (tid < 4) {
        float s = 0.f;
        const float* wv = w2 + tid * 64;
        #pragma unroll
        for (int k = 0; k < 64; k++) s += wv[k] * h1_sh[k];
        out[b * 4 + tid] = s + b2[tid];
    }
}

// ---------------------------------------------------------------------------
extern "C" void kernel_launch(void* const* d_in, const int* in_sizes, int n_in,
                              void* d_out, int out_size, void* d_ws, size_t ws_size,
                              hipStream_t stream)
{
    const float* x        = (const float*)d_in[0];
    const float* w_ih0    = (const float*)d_in[1];
    const float* w_ih_rest= (const float*)d_in[2];
    const float* w_hh     = (const float*)d_in[3];
    const float* b_ih     = (const float*)d_in[4];
    const float* b_hh     = (const float*)d_in[5];
    const float* w_attn   = (const float*)d_in[6];
    const float* b_attn   = (const float*)d_in[7];
    const float* w1       = (const float*)d_in[8];
    const float* b1       = (const float*)d_in[9];
    const float* w2       = (const float*)d_in[10];
    const float* b2       = (const float*)d_in[11];
    float* out = (float*)d_out;

    float* ws   = (float*)d_ws;
    float* hs   = ws;                       // B*T*H = 8388608 floats
    float* h_st = hs + (size_t)Bn * Tn * Hn;
    float* c_st = h_st + (size_t)Bn * Hn;
    float* pre  = c_st + (size_t)Bn * Hn;

    // pick largest T-chunk that fits in ws
    int tch = 512;
    while (tch > 16) {
        size_t need = ((size_t)Bn * Tn * Hn + 2 * (size_t)Bn * Hn +
                       (size_t)Bn * tch * Gn) * sizeof(float);
        if (need <= ws_size) break;
        tch >>= 1;
    }
    int tlog = 31 - __builtin_clz((unsigned)tch);

    for (int l = 0; l < Ln; l++) {
        const float* A = (l == 0) ? x : hs;
        int K = (l == 0) ? Dn : Hn;
        const float* W = (l == 0) ? w_ih0 : (w_ih_rest + (size_t)(l - 1) * Gn * Hn);
        const float* whl = w_hh + (size_t)l * Gn * Hn;
        for (int c = 0; c < Tn / tch; c++) {
            dim3 gg(tch, 4);   // M/128 = tch row tiles, 512/128 = 4 col tiles
            gemm_pre<<<gg, 256, 0, stream>>>(A, K, Tn * K, c * tch, tlog,
                                             W, b_ih + l * Gn, b_hh + l * Gn, pre);
            lstm_scan<<<Bn, 512, 0, stream>>>(pre, whl, hs, h_st, c_st,
                                              c * tch, tch, c == 0 ? 1 : 0);
        }
    }
    head_kernel<<<Bn, 256, 0, stream>>>(hs, w_attn, b_attn, w1, b1, w2, b2, out);
}

// Round 2
// 2346.764 us; speedup vs baseline: 1.2209x; 1.2209x over previous
//
#include <hip/hip_runtime.h>
#include <math.h>

#define Bn 128
#define Tn 512
#define Dn 32
#define Hn 128
#define Gn 512   // 4*H
#define Ln 3

// ---------------------------------------------------------------------------
// GEMM: pre[M, 512] = A_chunk[M, K] * W[512, K]^T + (b_ih + b_hh)
// ---------------------------------------------------------------------------
__global__ __launch_bounds__(256) void gemm_pre(
    const float* __restrict__ A, int K, int rowStrideB, int t0, int tlog,
    const float* __restrict__ W,
    const float* __restrict__ bi, const float* __restrict__ bh,
    float* __restrict__ C)
{
    __shared__ __align__(16) float As[8][128];
    __shared__ __align__(16) float Bs[8][128];
    const int tid  = threadIdx.x;
    const int row0 = blockIdx.x * 128;
    const int col0 = blockIdx.y * 128;
    const int ty = tid >> 4, tx = tid & 15;
    const int lr = tid >> 1, lk = (tid & 1) * 4;
    const int tmask = (1 << tlog) - 1;

    float acc[8][8];
    #pragma unroll
    for (int i = 0; i < 8; i++)
        #pragma unroll
        for (int j = 0; j < 8; j++) acc[i][j] = 0.f;

    for (int k0 = 0; k0 < K; k0 += 8) {
        {
            int rg = row0 + lr;
            int b_idx = rg >> tlog;
            int tt = rg & tmask;
            const float* ap = A + (size_t)b_idx * rowStrideB +
                              (size_t)(t0 + tt) * K + (k0 + lk);
            float4 av = *(const float4*)ap;
            As[lk + 0][lr] = av.x; As[lk + 1][lr] = av.y;
            As[lk + 2][lr] = av.z; As[lk + 3][lr] = av.w;
            const float* wp = W + (size_t)(col0 + lr) * K + (k0 + lk);
            float4 wv = *(const float4*)wp;
            Bs[lk + 0][lr] = wv.x; Bs[lk + 1][lr] = wv.y;
            Bs[lk + 2][lr] = wv.z; Bs[lk + 3][lr] = wv.w;
        }
        __syncthreads();
        #pragma unroll
        for (int kk = 0; kk < 8; kk++) {
            float4 a0 = *(const float4*)&As[kk][ty * 8];
            float4 a1 = *(const float4*)&As[kk][ty * 8 + 4];
            float4 b0 = *(const float4*)&Bs[kk][tx * 8];
            float4 b1v = *(const float4*)&Bs[kk][tx * 8 + 4];
            float av[8] = {a0.x, a0.y, a0.z, a0.w, a1.x, a1.y, a1.z, a1.w};
            float bv[8] = {b0.x, b0.y, b0.z, b0.w, b1v.x, b1v.y, b1v.z, b1v.w};
            #pragma unroll
            for (int i = 0; i < 8; i++)
                #pragma unroll
                for (int j = 0; j < 8; j++) acc[i][j] += av[i] * bv[j];
        }
        __syncthreads();
    }
    #pragma unroll
    for (int i = 0; i < 8; i++) {
        int r = row0 + ty * 8 + i;
        #pragma unroll
        for (int j = 0; j < 8; j += 4) {
            int g = col0 + tx * 8 + j;
            float4 o;
            o.x = acc[i][j + 0] + bi[g + 0] + bh[g + 0];
            o.y = acc[i][j + 1] + bi[g + 1] + bh[g + 1];
            o.z = acc[i][j + 2] + bi[g + 2] + bh[g + 2];
            o.w = acc[i][j + 3] + bi[g + 3] + bh[g + 3];
            *(float4*)&C[(size_t)r * Gn + g] = o;
        }
    }
}

// ---------------------------------------------------------------------------
// LSTM scan. One block per batch item, 512 threads = one per gate.
// h broadcast via v_readlane (SGPR) -> v_fmac scalar operand: no per-k LDS.
// w_hh row (128 floats) held in VGPRs (launch_bounds(512,2) -> 256 VGPR cap).
// c-state lives in registers of threads < 128.
// ---------------------------------------------------------------------------
__device__ __forceinline__ float bcast(float v, int l) {
    return __int_as_float(__builtin_amdgcn_readlane(__float_as_int(v), l));
}
__device__ __forceinline__ float sigm(float x) {
    return 1.f / (1.f + __expf(-x));
}
__device__ __forceinline__ float tanh_fast(float x) {
    return 1.f - 2.f / (1.f + __expf(2.f * x));
}

__global__ __launch_bounds__(512, 2) void lstm_scan(
    const float* __restrict__ pre,     // [B*TCH, 512]
    const float* __restrict__ w_hh,    // [512, 128] (this layer)
    float* __restrict__ hs,            // [B, T, H] layer output
    float* __restrict__ h_state, float* __restrict__ c_state,
    int t0, int TCH, int first)
{
    const int b = blockIdx.x;
    const int g = threadIdx.x;
    const int lane = g & 63;
    __shared__ __align__(16) float h_sh[Hn];
    __shared__ __align__(16) float gates[Gn];

    float w[128];
    {
        const float4* wp = (const float4*)(w_hh + (size_t)g * Hn);
        #pragma unroll
        for (int k = 0; k < 32; k++) {
            float4 v = wp[k];
            w[4 * k + 0] = v.x; w[4 * k + 1] = v.y;
            w[4 * k + 2] = v.z; w[4 * k + 3] = v.w;
        }
    }

    float cr = 0.f;
    if (g < Hn) {
        float hv = 0.f;
        if (!first) {
            hv = h_state[b * Hn + g];
            cr = c_state[b * Hn + g];
        }
        h_sh[g] = hv;
    }
    __syncthreads();

    const float* preb = pre + (size_t)b * TCH * Gn + g;
    float* hsb = hs + ((size_t)b * Tn + t0) * Hn;

    for (int t = 0; t < TCH; t++) {
        float pv = preb[(size_t)t * Gn];          // issued early, used late
        float h0 = h_sh[lane];
        float h1 = h_sh[lane + 64];
        float acc0 = 0.f, acc1 = 0.f;
        #pragma unroll
        for (int k = 0; k < 64; k++) acc0 += bcast(h0, k) * w[k];
        #pragma unroll
        for (int k = 0; k < 64; k++) acc1 += bcast(h1, k) * w[64 + k];
        float acc = acc0 + acc1 + pv;

        float act;
        if (g < 256)      act = sigm(acc);        // i, f (wave-uniform branch)
        else if (g < 384) act = tanh_fast(acc);   // g
        else              act = sigm(acc);        // o
        gates[g] = act;
        __syncthreads();

        if (g < Hn) {
            float iv = gates[g], fv = gates[Hn + g];
            float gv = gates[2 * Hn + g], ov = gates[3 * Hn + g];
            cr = fv * cr + iv * gv;
            float h = ov * tanh_fast(cr);
            h_sh[g] = h;
            hsb[(size_t)t * Hn + g] = h;
        }
        __syncthreads();
    }
    if (g < Hn) {
        h_state[b * Hn + g] = h_sh[g];
        c_state[b * Hn + g] = cr;
    }
}

// ---------------------------------------------------------------------------
// Attention pooling + MLP head. One block per batch item, 256 threads.
// ---------------------------------------------------------------------------
__global__ __launch_bounds__(256) void head_kernel(
    const float* __restrict__ hs,
    const float* __restrict__ w_attn, const float* __restrict__ b_attn,
    const float* __restrict__ w1, const float* __restrict__ b1,
    const float* __restrict__ w2, const float* __restrict__ b2,
    float* __restrict__ out)
{
    const int b = blockIdx.x;
    const int tid = threadIdx.x;
    __shared__ __align__(16) float wa_sh[Hn];
    __shared__ __align__(16) float sc[Tn];
    __shared__ __align__(16) float red[256];
    __shared__ __align__(16) float ctx_sh[Hn];
    __shared__ __align__(16) float h1_sh[64];

    if (tid < Hn) wa_sh[tid] = w_attn[tid];
    __syncthreads();

    const float* hb = hs + (size_t)b * Tn * Hn;

    for (int t = tid; t < Tn; t += 256) {
        const float4* hv = (const float4*)(hb + (size_t)t * Hn);
        const float4* wv = (const float4*)wa_sh;
        float s = 0.f;
        #pragma unroll
        for (int k = 0; k < 32; k++) {
            float4 h4 = hv[k], w4 = wv[k];
            s += h4.x * w4.x + h4.y * w4.y + h4.z * w4.z + h4.w * w4.w;
        }
        sc[t] = s + b_attn[0];
    }
    __syncthreads();

    float m = fmaxf(sc[tid], sc[tid + 256]);
    red[tid] = m; __syncthreads();
    for (int s_ = 128; s_ > 0; s_ >>= 1) {
        if (tid < s_) red[tid] = fmaxf(red[tid], red[tid + s_]);
        __syncthreads();
    }
    float mx = red[0];
    __syncthreads();
    float e0 = __expf(sc[tid] - mx), e1 = __expf(sc[tid + 256] - mx);
    sc[tid] = e0; sc[tid + 256] = e1;
    red[tid] = e0 + e1; __syncthreads();
    for (int s_ = 128; s_ > 0; s_ >>= 1) {
        if (tid < s_) red[tid] += red[tid + s_];
        __syncthreads();
    }
    float inv = 1.f / red[0];
    __syncthreads();

    {
        int j = tid & 127, half = tid >> 7;
        float a = 0.f;
        for (int t = half * 256; t < half * 256 + 256; t++)
            a += sc[t] * hb[(size_t)t * Hn + j];
        red[tid] = a;
        __syncthreads();
        if (tid < Hn) ctx_sh[tid] = (red[tid] + red[tid + Hn]) * inv;
        __syncthreads();
    }

    if (tid < 64) {
        const float4* wv = (const float4*)(w1 + (size_t)tid * Hn);
        const float4* cv = (const float4*)ctx_sh;
        float s = 0.f;
        #pragma unroll
        for (int k = 0; k < 32; k++) {
            float4 a = wv[k], c = cv[k];
            s += a.x * c.x + a.y * c.y + a.z * c.z + a.w * c.w;
        }
        h1_sh[tid] = fmaxf(s + b1[tid], 0.f);
    }
    __syncthreads();

    if (tid < 4) {
        float s = 0.f;
        const float* wv = w2 + tid * 64;
        #pragma unroll
        for (int k = 0; k < 64; k++) s += wv[k] * h1_sh[k];
        out[b * 4 + tid] = s + b2[tid];
    }
}

// ---------------------------------------------------------------------------
extern "C" void kernel_launch(void* const* d_in, const int* in_sizes, int n_in,
                              void* d_out, int out_size, void* d_ws, size_t ws_size,
                              hipStream_t stream)
{
    const float* x        = (const float*)d_in[0];
    const float* w_ih0    = (const float*)d_in[1];
    const float* w_ih_rest= (const float*)d_in[2];
    const float* w_hh     = (const float*)d_in[3];
    const float* b_ih     = (const float*)d_in[4];
    const float* b_hh     = (const float*)d_in[5];
    const float* w_attn   = (const float*)d_in[6];
    const float* b_attn   = (const float*)d_in[7];
    const float* w1       = (const float*)d_in[8];
    const float* b1       = (const float*)d_in[9];
    const float* w2       = (const float*)d_in[10];
    const float* b2       = (const float*)d_in[11];
    float* out = (float*)d_out;

    float* ws   = (float*)d_ws;
    float* hs   = ws;                       // B*T*H floats
    float* h_st = hs + (size_t)Bn * Tn * Hn;
    float* c_st = h_st + (size_t)Bn * Hn;
    float* pre  = c_st + (size_t)Bn * Hn;

    int tch = 512;
    while (tch > 16) {
        size_t need = ((size_t)Bn * Tn * Hn + 2 * (size_t)Bn * Hn +
                       (size_t)Bn * tch * Gn) * sizeof(float);
        if (need <= ws_size) break;
        tch >>= 1;
    }
    int tlog = 31 - __builtin_clz((unsigned)tch);

    for (int l = 0; l < Ln; l++) {
        const float* A = (l == 0) ? x : hs;
        int K = (l == 0) ? Dn : Hn;
        const float* W = (l == 0) ? w_ih0 : (w_ih_rest + (size_t)(l - 1) * Gn * Hn);
        const float* whl = w_hh + (size_t)l * Gn * Hn;
        for (int c = 0; c < Tn / tch; c++) {
            dim3 gg(tch, 4);
            gemm_pre<<<gg, 256, 0, stream>>>(A, K, Tn * K, c * tch, tlog,
                                             W, b_ih + l * Gn, b_hh + l * Gn, pre);
            lstm_scan<<<Bn, 512, 0, stream>>>(pre, whl, hs, h_st, c_st,
                                              c * tch, tch, c == 0 ? 1 : 0);
        }
    }
    head_kernel<<<Bn, 256, 0, stream>>>(hs, w_attn, b_attn, w1, b1, w2, b2, out);
}

// Round 3
// 2302.789 us; speedup vs baseline: 1.2442x; 1.0191x over previous
//
#include <hip/hip_runtime.h>
#include <math.h>

#define Bn 128
#define Tn 512
#define Dn 32
#define Hn 128
#define Gn 512   // 4*H
#define Ln 3

// LDS-only barrier: does NOT drain vmcnt, so global prefetch loads and
// h-trajectory stores stay in flight across it. "memory" clobber stops the
// compiler reordering LDS ops around it.
#define BAR_LDS() asm volatile("s_waitcnt lgkmcnt(0)\n\ts_barrier" ::: "memory")

// ---------------------------------------------------------------------------
// GEMM: pre[M, 512] = A_chunk[M, K] * W[512, K]^T + (b_ih + b_hh)
// ---------------------------------------------------------------------------
__global__ __launch_bounds__(256) void gemm_pre(
    const float* __restrict__ A, int K, int rowStrideB, int t0, int tlog,
    const float* __restrict__ W,
    const float* __restrict__ bi, const float* __restrict__ bh,
    float* __restrict__ C)
{
    __shared__ __align__(16) float As[8][128];
    __shared__ __align__(16) float Bs[8][128];
    const int tid  = threadIdx.x;
    const int row0 = blockIdx.x * 128;
    const int col0 = blockIdx.y * 128;
    const int ty = tid >> 4, tx = tid & 15;
    const int lr = tid >> 1, lk = (tid & 1) * 4;
    const int tmask = (1 << tlog) - 1;

    float acc[8][8];
    #pragma unroll
    for (int i = 0; i < 8; i++)
        #pragma unroll
        for (int j = 0; j < 8; j++) acc[i][j] = 0.f;

    for (int k0 = 0; k0 < K; k0 += 8) {
        {
            int rg = row0 + lr;
            int b_idx = rg >> tlog;
            int tt = rg & tmask;
            const float* ap = A + (size_t)b_idx * rowStrideB +
                              (size_t)(t0 + tt) * K + (k0 + lk);
            float4 av = *(const float4*)ap;
            As[lk + 0][lr] = av.x; As[lk + 1][lr] = av.y;
            As[lk + 2][lr] = av.z; As[lk + 3][lr] = av.w;
            const float* wp = W + (size_t)(col0 + lr) * K + (k0 + lk);
            float4 wv = *(const float4*)wp;
            Bs[lk + 0][lr] = wv.x; Bs[lk + 1][lr] = wv.y;
            Bs[lk + 2][lr] = wv.z; Bs[lk + 3][lr] = wv.w;
        }
        __syncthreads();
        #pragma unroll
        for (int kk = 0; kk < 8; kk++) {
            float4 a0 = *(const float4*)&As[kk][ty * 8];
            float4 a1 = *(const float4*)&As[kk][ty * 8 + 4];
            float4 b0 = *(const float4*)&Bs[kk][tx * 8];
            float4 b1v = *(const float4*)&Bs[kk][tx * 8 + 4];
            float av[8] = {a0.x, a0.y, a0.z, a0.w, a1.x, a1.y, a1.z, a1.w};
            float bv[8] = {b0.x, b0.y, b0.z, b0.w, b1v.x, b1v.y, b1v.z, b1v.w};
            #pragma unroll
            for (int i = 0; i < 8; i++)
                #pragma unroll
                for (int j = 0; j < 8; j++) acc[i][j] += av[i] * bv[j];
        }
        __syncthreads();
    }
    #pragma unroll
    for (int i = 0; i < 8; i++) {
        int r = row0 + ty * 8 + i;
        #pragma unroll
        for (int j = 0; j < 8; j += 4) {
            int g = col0 + tx * 8 + j;
            float4 o;
            o.x = acc[i][j + 0] + bi[g + 0] + bh[g + 0];
            o.y = acc[i][j + 1] + bi[g + 1] + bh[g + 1];
            o.z = acc[i][j + 2] + bi[g + 2] + bh[g + 2];
            o.w = acc[i][j + 3] + bi[g + 3] + bh[g + 3];
            *(float4*)&C[(size_t)r * Gn + g] = o;
        }
    }
}

// ---------------------------------------------------------------------------
// LSTM scan. One block per batch item, 512 threads = one per gate.
// h broadcast via v_readlane; w_hh row in registers. All threads do the
// c/h update redundantly for unit j=g&127 (no idle waves); barriers are
// LDS-only so pre-prefetch and h-stores stay in flight.
// ---------------------------------------------------------------------------
__device__ __forceinline__ float bcast(float v, int l) {
    return __int_as_float(__builtin_amdgcn_readlane(__float_as_int(v), l));
}
__device__ __forceinline__ float sigm(float x) {
    return 1.f / (1.f + __expf(-x));
}
__device__ __forceinline__ float tanh_fast(float x) {
    return 1.f - 2.f / (1.f + __expf(2.f * x));
}

__global__ __launch_bounds__(512, 2) void lstm_scan(
    const float* __restrict__ pre,     // [B*TCH, 512]
    const float* __restrict__ w_hh,    // [512, 128] (this layer)
    float* __restrict__ hs,            // [B, T, H] layer output
    float* __restrict__ h_state, float* __restrict__ c_state,
    int t0, int TCH, int first)
{
    const int b    = blockIdx.x;
    const int g    = threadIdx.x;
    const int lane = g & 63;
    const int j    = g & 127;           // hidden unit this thread finalizes
    const int wv_id = g >> 6;
    const bool lower = ((wv_id & 1) == 0);   // even waves own h[lane]

    __shared__ __align__(16) float h_sh[Hn];
    __shared__ __align__(16) float gsh[Gn];

    float w[128];
    {
        const float4* wp = (const float4*)(w_hh + (size_t)g * Hn);
        #pragma unroll
        for (int k = 0; k < 32; k++) {
            float4 v = wp[k];
            w[4 * k + 0] = v.x; w[4 * k + 1] = v.y;
            w[4 * k + 2] = v.z; w[4 * k + 3] = v.w;
        }
    }

    float h0, h1, cr;
    if (first) {
        h0 = 0.f; h1 = 0.f; cr = 0.f;
    } else {
        h0 = h_state[b * Hn + lane];
        h1 = h_state[b * Hn + 64 + lane];
        cr = c_state[b * Hn + j];
    }

    const float* pp = pre + (size_t)b * TCH * Gn + g;
    float* hsb = hs + ((size_t)b * Tn + t0) * Hn;

    float pv0 = pp[0];
    float pv1 = (TCH > 1) ? pp[Gn] : pv0;

    for (int t = 0; t < TCH; t++) {
        float pv = pv0;
        pv0 = pv1;
        int tn = (t + 2 < TCH) ? (t + 2) : (TCH - 1);
        pv1 = pp[(size_t)tn * Gn];     // in flight until next iteration

        float a0 = 0.f, a1 = 0.f, a2 = 0.f, a3 = 0.f;
        #pragma unroll
        for (int k = 0; k < 32; k++) {
            a0 += bcast(h0, k)      * w[k];
            a1 += bcast(h0, k + 32) * w[k + 32];
            a2 += bcast(h1, k)      * w[k + 64];
            a3 += bcast(h1, k + 32) * w[k + 96];
        }
        float acc = ((a0 + a1) + (a2 + a3)) + pv;

        float act;
        if (g < 256)      act = sigm(acc);        // i, f (wave-uniform)
        else if (g < 384) act = tanh_fast(acc);   // g
        else              act = sigm(acc);        // o
        gsh[g] = act;
        BAR_LDS();

        float iv = gsh[j];
        float fv = gsh[Hn + j];
        float gg = gsh[2 * Hn + j];
        float ov = gsh[3 * Hn + j];
        cr = fv * cr + iv * gg;                   // redundant across quads
        float hnew = ov * tanh_fast(cr);
        if (g < Hn) {
            h_sh[g] = hnew;
            hsb[(size_t)t * Hn + g] = hnew;       // store stays in flight
        }
        BAR_LDS();

        h0 = lower ? hnew : h_sh[lane];
        h1 = lower ? h_sh[lane + 64] : hnew;
    }

    if (g < Hn) {
        h_state[b * Hn + g] = lower ? h0 : h1;    // == hnew for unit g
        c_state[b * Hn + g] = cr;
    }
}

// ---------------------------------------------------------------------------
// Attention pooling + MLP head. One block per batch item, 256 threads.
// ---------------------------------------------------------------------------
__global__ __launch_bounds__(256) void head_kernel(
    const float* __restrict__ hs,
    const float* __restrict__ w_attn, const float* __restrict__ b_attn,
    const float* __restrict__ w1, const float* __restrict__ b1,
    const float* __restrict__ w2, const float* __restrict__ b2,
    float* __restrict__ out)
{
    const int b = blockIdx.x;
    const int tid = threadIdx.x;
    __shared__ __align__(16) float wa_sh[Hn];
    __shared__ __align__(16) float sc[Tn];
    __shared__ __align__(16) float red[256];
    __shared__ __align__(16) float ctx_sh[Hn];
    __shared__ __align__(16) float h1_sh[64];

    if (tid < Hn) wa_sh[tid] = w_attn[tid];
    __syncthreads();

    const float* hb = hs + (size_t)b * Tn * Hn;

    for (int t = tid; t < Tn; t += 256) {
        const float4* hv = (const float4*)(hb + (size_t)t * Hn);
        const float4* wvv = (const float4*)wa_sh;
        float s = 0.f;
        #pragma unroll
        for (int k = 0; k < 32; k++) {
            float4 h4 = hv[k], w4 = wvv[k];
            s += h4.x * w4.x + h4.y * w4.y + h4.z * w4.z + h4.w * w4.w;
        }
        sc[t] = s + b_attn[0];
    }
    __syncthreads();

    float m = fmaxf(sc[tid], sc[tid + 256]);
    red[tid] = m; __syncthreads();
    for (int s_ = 128; s_ > 0; s_ >>= 1) {
        if (tid < s_) red[tid] = fmaxf(red[tid], red[tid + s_]);
        __syncthreads();
    }
    float mx = red[0];
    __syncthreads();
    float e0 = __expf(sc[tid] - mx), e1 = __expf(sc[tid + 256] - mx);
    sc[tid] = e0; sc[tid + 256] = e1;
    red[tid] = e0 + e1; __syncthreads();
    for (int s_ = 128; s_ > 0; s_ >>= 1) {
        if (tid < s_) red[tid] += red[tid + s_];
        __syncthreads();
    }
    float inv = 1.f / red[0];
    __syncthreads();

    {
        int jj = tid & 127, half = tid >> 7;
        float a = 0.f;
        for (int t = half * 256; t < half * 256 + 256; t++)
            a += sc[t] * hb[(size_t)t * Hn + jj];
        red[tid] = a;
        __syncthreads();
        if (tid < Hn) ctx_sh[tid] = (red[tid] + red[tid + Hn]) * inv;
        __syncthreads();
    }

    if (tid < 64) {
        const float4* wvv = (const float4*)(w1 + (size_t)tid * Hn);
        const float4* cv = (const float4*)ctx_sh;
        float s = 0.f;
        #pragma unroll
        for (int k = 0; k < 32; k++) {
            float4 a = wvv[k], c = cv[k];
            s += a.x * c.x + a.y * c.y + a.z * c.z + a.w * c.w;
        }
        h1_sh[tid] = fmaxf(s + b1[tid], 0.f);
    }
    __syncthreads();

    if (tid < 4) {
        float s = 0.f;
        const float* wvv = w2 + tid * 64;
        #pragma unroll
        for (int k = 0; k < 64; k++) s += wvv[k] * h1_sh[k];
        out[b * 4 + tid] = s + b2[tid];
    }
}

// ---------------------------------------------------------------------------
extern "C" void kernel_launch(void* const* d_in, const int* in_sizes, int n_in,
                              void* d_out, int out_size, void* d_ws, size_t ws_size,
                              hipStream_t stream)
{
    const float* x        = (const float*)d_in[0];
    const float* w_ih0    = (const float*)d_in[1];
    const float* w_ih_rest= (const float*)d_in[2];
    const float* w_hh     = (const float*)d_in[3];
    const float* b_ih     = (const float*)d_in[4];
    const float* b_hh     = (const float*)d_in[5];
    const float* w_attn   = (const float*)d_in[6];
    const float* b_attn   = (const float*)d_in[7];
    const float* w1       = (const float*)d_in[8];
    const float* b1       = (const float*)d_in[9];
    const float* w2       = (const float*)d_in[10];
    const float* b2       = (const float*)d_in[11];
    float* out = (float*)d_out;

    float* ws   = (float*)d_ws;
    float* hs   = ws;
    float* h_st = hs + (size_t)Bn * Tn * Hn;
    float* c_st = h_st + (size_t)Bn * Hn;
    float* pre  = c_st + (size_t)Bn * Hn;

    int tch = 512;
    while (tch > 16) {
        size_t need = ((size_t)Bn * Tn * Hn + 2 * (size_t)Bn * Hn +
                       (size_t)Bn * tch * Gn) * sizeof(float);
        if (need <= ws_size) break;
        tch >>= 1;
    }
    int tlog = 31 - __builtin_clz((unsigned)tch);

    for (int l = 0; l < Ln; l++) {
        const float* A = (l == 0) ? x : hs;
        int K = (l == 0) ? Dn : Hn;
        const float* W = (l == 0) ? w_ih0 : (w_ih_rest + (size_t)(l - 1) * Gn * Hn);
        const float* whl = w_hh + (size_t)l * Gn * Hn;
        for (int c = 0; c < Tn / tch; c++) {
            dim3 gg(tch, 4);
            gemm_pre<<<gg, 256, 0, stream>>>(A, K, Tn * K, c * tch, tlog,
                                             W, b_ih + l * Gn, b_hh + l * Gn, pre);
            lstm_scan<<<Bn, 512, 0, stream>>>(pre, whl, hs, h_st, c_st,
                                              c * tch, tch, c == 0 ? 1 : 0);
        }
    }
    head_kernel<<<Bn, 256, 0, stream>>>(hs, w_attn, b_attn, w1, b1, w2, b2, out);
}

// Round 4
// 2229.268 us; speedup vs baseline: 1.2852x; 1.0330x over previous
//
#include <hip/hip_runtime.h>
#include <math.h>

#define Bn 128
#define Tn 512
#define Dn 32
#define Hn 128
#define Gn 512   // 4*H
#define Ln 3

// LDS-only barrier: does NOT drain vmcnt.
#define BAR_LDS() asm volatile("s_waitcnt lgkmcnt(0)\n\ts_barrier" ::: "memory")

typedef float vf32 __attribute__((ext_vector_type(32)));

// ---------------------------------------------------------------------------
// GEMM: pre[M, 512] = A_chunk[M, K] * W[512, K]^T + (b_ih + b_hh)
// ---------------------------------------------------------------------------
__global__ __launch_bounds__(256) void gemm_pre(
    const float* __restrict__ A, int K, int rowStrideB, int t0, int tlog,
    const float* __restrict__ W,
    const float* __restrict__ bi, const float* __restrict__ bh,
    float* __restrict__ C)
{
    __shared__ __align__(16) float As[8][128];
    __shared__ __align__(16) float Bs[8][128];
    const int tid  = threadIdx.x;
    const int row0 = blockIdx.x * 128;
    const int col0 = blockIdx.y * 128;
    const int ty = tid >> 4, tx = tid & 15;
    const int lr = tid >> 1, lk = (tid & 1) * 4;
    const int tmask = (1 << tlog) - 1;

    float acc[8][8];
    #pragma unroll
    for (int i = 0; i < 8; i++)
        #pragma unroll
        for (int j = 0; j < 8; j++) acc[i][j] = 0.f;

    for (int k0 = 0; k0 < K; k0 += 8) {
        {
            int rg = row0 + lr;
            int b_idx = rg >> tlog;
            int tt = rg & tmask;
            const float* ap = A + (size_t)b_idx * rowStrideB +
                              (size_t)(t0 + tt) * K + (k0 + lk);
            float4 av = *(const float4*)ap;
            As[lk + 0][lr] = av.x; As[lk + 1][lr] = av.y;
            As[lk + 2][lr] = av.z; As[lk + 3][lr] = av.w;
            const float* wp = W + (size_t)(col0 + lr) * K + (k0 + lk);
            float4 wv = *(const float4*)wp;
            Bs[lk + 0][lr] = wv.x; Bs[lk + 1][lr] = wv.y;
            Bs[lk + 2][lr] = wv.z; Bs[lk + 3][lr] = wv.w;
        }
        __syncthreads();
        #pragma unroll
        for (int kk = 0; kk < 8; kk++) {
            float4 a0 = *(const float4*)&As[kk][ty * 8];
            float4 a1 = *(const float4*)&As[kk][ty * 8 + 4];
            float4 b0 = *(const float4*)&Bs[kk][tx * 8];
            float4 b1v = *(const float4*)&Bs[kk][tx * 8 + 4];
            float av[8] = {a0.x, a0.y, a0.z, a0.w, a1.x, a1.y, a1.z, a1.w};
            float bv[8] = {b0.x, b0.y, b0.z, b0.w, b1v.x, b1v.y, b1v.z, b1v.w};
            #pragma unroll
            for (int i = 0; i < 8; i++)
                #pragma unroll
                for (int j = 0; j < 8; j++) acc[i][j] += av[i] * bv[j];
        }
        __syncthreads();
    }
    #pragma unroll
    for (int i = 0; i < 8; i++) {
        int r = row0 + ty * 8 + i;
        #pragma unroll
        for (int j = 0; j < 8; j += 4) {
            int g = col0 + tx * 8 + j;
            float4 o;
            o.x = acc[i][j + 0] + bi[g + 0] + bh[g + 0];
            o.y = acc[i][j + 1] + bi[g + 1] + bh[g + 1];
            o.z = acc[i][j + 2] + bi[g + 2] + bh[g + 2];
            o.w = acc[i][j + 3] + bi[g + 3] + bh[g + 3];
            *(float4*)&C[(size_t)r * Gn + g] = o;
        }
    }
}

// ---------------------------------------------------------------------------
// LSTM scan. One block per batch item, 512 threads = one per gate.
// w_hh row FORCED into VGPRs via ext_vector_type(32) SSA values (a plain
// float w[128] array is left in scratch by SROA -> 256KB/block/step of L2
// traffic, which was the R2/R3 bottleneck). h broadcast via v_readlane.
// ---------------------------------------------------------------------------
__device__ __forceinline__ float bcast(float v, int l) {
    return __int_as_float(__builtin_amdgcn_readlane(__float_as_int(v), l));
}
__device__ __forceinline__ float sigm(float x) {
    return __builtin_amdgcn_rcpf(1.f + __expf(-x));
}
__device__ __forceinline__ float tanh_fast(float x) {
    return 1.f - 2.f * __builtin_amdgcn_rcpf(1.f + __expf(2.f * x));
}

__global__ __launch_bounds__(512, 2) void lstm_scan(
    const float* __restrict__ pre,     // [B*TCH, 512]
    const float* __restrict__ w_hh,    // [512, 128] (this layer)
    float* __restrict__ hs,            // [B, T, H] layer output
    float* __restrict__ h_state, float* __restrict__ c_state,
    int t0, int TCH, int first)
{
    const int b    = blockIdx.x;
    const int g    = threadIdx.x;
    const int lane = g & 63;
    const int j    = g & 127;           // hidden unit this thread finalizes
    const int wv_id = g >> 6;
    const bool lower = ((wv_id & 1) == 0);   // even waves own h[lane]

    __shared__ __align__(16) float h_sh[Hn];
    __shared__ __align__(16) float gsh[Gn];

    vf32 wA, wB, wC, wD;   // w_hh row: k in [0,32) [32,64) [64,96) [96,128)
    {
        const float4* wp = (const float4*)(w_hh + (size_t)g * Hn);
        #pragma unroll
        for (int k = 0; k < 8; k++) {
            float4 v0 = wp[k], v1 = wp[k + 8], v2 = wp[k + 16], v3 = wp[k + 24];
            wA[4 * k + 0] = v0.x; wA[4 * k + 1] = v0.y;
            wA[4 * k + 2] = v0.z; wA[4 * k + 3] = v0.w;
            wB[4 * k + 0] = v1.x; wB[4 * k + 1] = v1.y;
            wB[4 * k + 2] = v1.z; wB[4 * k + 3] = v1.w;
            wC[4 * k + 0] = v2.x; wC[4 * k + 1] = v2.y;
            wC[4 * k + 2] = v2.z; wC[4 * k + 3] = v2.w;
            wD[4 * k + 0] = v3.x; wD[4 * k + 1] = v3.y;
            wD[4 * k + 2] = v3.z; wD[4 * k + 3] = v3.w;
        }
    }

    float h0, h1, cr;
    if (first) {
        h0 = 0.f; h1 = 0.f; cr = 0.f;
    } else {
        h0 = h_state[b * Hn + lane];
        h1 = h_state[b * Hn + 64 + lane];
        cr = c_state[b * Hn + j];
    }

    const float* pp = pre + (size_t)b * TCH * Gn + g;
    float* hsb = hs + ((size_t)b * Tn + t0) * Hn;

    float pv0 = pp[0];
    float pv1 = (TCH > 1) ? pp[Gn] : pv0;

    for (int t = 0; t < TCH; t++) {
        float pv = pv0;
        pv0 = pv1;
        int tn = (t + 2 < TCH) ? (t + 2) : (TCH - 1);
        pv1 = pp[(size_t)tn * Gn];     // in flight until next iteration

        float a0 = 0.f, a1 = 0.f, a2 = 0.f, a3 = 0.f;
        #pragma unroll
        for (int k = 0; k < 32; k++) {
            a0 += bcast(h0, k)      * wA[k];
            a1 += bcast(h0, k + 32) * wB[k];
            a2 += bcast(h1, k)      * wC[k];
            a3 += bcast(h1, k + 32) * wD[k];
        }
        float acc = ((a0 + a1) + (a2 + a3)) + pv;

        float act;
        if (g < 256)      act = sigm(acc);        // i, f (wave-uniform)
        else if (g < 384) act = tanh_fast(acc);   // g
        else              act = sigm(acc);        // o
        gsh[g] = act;
        BAR_LDS();

        float iv = gsh[j];
        float fv = gsh[Hn + j];
        float gg = gsh[2 * Hn + j];
        float ov = gsh[3 * Hn + j];
        cr = fv * cr + iv * gg;                   // redundant across quads
        float hnew = ov * tanh_fast(cr);
        if (g < Hn) {
            h_sh[g] = hnew;
            hsb[(size_t)t * Hn + g] = hnew;       // store stays in flight
        }
        BAR_LDS();

        h0 = lower ? hnew : h_sh[lane];
        h1 = lower ? h_sh[lane + 64] : hnew;
    }

    if (g < Hn) {
        h_state[b * Hn + g] = lower ? h0 : h1;    // == hnew for unit g
        c_state[b * Hn + g] = cr;
    }
}

// ---------------------------------------------------------------------------
// Attention pooling + MLP head. One block per batch item, 256 threads.
// ---------------------------------------------------------------------------
__global__ __launch_bounds__(256) void head_kernel(
    const float* __restrict__ hs,
    const float* __restrict__ w_attn, const float* __restrict__ b_attn,
    const float* __restrict__ w1, const float* __restrict__ b1,
    const float* __restrict__ w2, const float* __restrict__ b2,
    float* __restrict__ out)
{
    const int b = blockIdx.x;
    const int tid = threadIdx.x;
    __shared__ __align__(16) float wa_sh[Hn];
    __shared__ __align__(16) float sc[Tn];
    __shared__ __align__(16) float red[256];
    __shared__ __align__(16) float ctx_sh[Hn];
    __shared__ __align__(16) float h1_sh[64];

    if (tid < Hn) wa_sh[tid] = w_attn[tid];
    __syncthreads();

    const float* hb = hs + (size_t)b * Tn * Hn;

    for (int t = tid; t < Tn; t += 256) {
        const float4* hv = (const float4*)(hb + (size_t)t * Hn);
        const float4* wvv = (const float4*)wa_sh;
        float s = 0.f;
        #pragma unroll
        for (int k = 0; k < 32; k++) {
            float4 h4 = hv[k], w4 = wvv[k];
            s += h4.x * w4.x + h4.y * w4.y + h4.z * w4.z + h4.w * w4.w;
        }
        sc[t] = s + b_attn[0];
    }
    __syncthreads();

    float m = fmaxf(sc[tid], sc[tid + 256]);
    red[tid] = m; __syncthreads();
    for (int s_ = 128; s_ > 0; s_ >>= 1) {
        if (tid < s_) red[tid] = fmaxf(red[tid], red[tid + s_]);
        __syncthreads();
    }
    float mx = red[0];
    __syncthreads();
    float e0 = __expf(sc[tid] - mx), e1 = __expf(sc[tid + 256] - mx);
    sc[tid] = e0; sc[tid + 256] = e1;
    red[tid] = e0 + e1; __syncthreads();
    for (int s_ = 128; s_ > 0; s_ >>= 1) {
        if (tid < s_) red[tid] += red[tid + s_];
        __syncthreads();
    }
    float inv = 1.f / red[0];
    __syncthreads();

    {
        int jj = tid & 127, half = tid >> 7;
        float a = 0.f;
        for (int t = half * 256; t < half * 256 + 256; t++)
            a += sc[t] * hb[(size_t)t * Hn + jj];
        red[tid] = a;
        __syncthreads();
        if (tid < Hn) ctx_sh[tid] = (red[tid] + red[tid + Hn]) * inv;
        __syncthreads();
    }

    if (tid < 64) {
        const float4* wvv = (const float4*)(w1 + (size_t)tid * Hn);
        const float4* cv = (const float4*)ctx_sh;
        float s = 0.f;
        #pragma unroll
        for (int k = 0; k < 32; k++) {
            float4 a = wvv[k], c = cv[k];
            s += a.x * c.x + a.y * c.y + a.z * c.z + a.w * c.w;
        }
        h1_sh[tid] = fmaxf(s + b1[tid], 0.f);
    }
    __syncthreads();

    if (tid < 4) {
        float s = 0.f;
        const float* wvv = w2 + tid * 64;
        #pragma unroll
        for (int k = 0; k < 64; k++) s += wvv[k] * h1_sh[k];
        out[b * 4 + tid] = s + b2[tid];
    }
}

// ---------------------------------------------------------------------------
extern "C" void kernel_launch(void* const* d_in, const int* in_sizes, int n_in,
                              void* d_out, int out_size, void* d_ws, size_t ws_size,
                              hipStream_t stream)
{
    const float* x        = (const float*)d_in[0];
    const float* w_ih0    = (const float*)d_in[1];
    const float* w_ih_rest= (const float*)d_in[2];
    const float* w_hh     = (const float*)d_in[3];
    const float* b_ih     = (const float*)d_in[4];
    const float* b_hh     = (const float*)d_in[5];
    const float* w_attn   = (const float*)d_in[6];
    const float* b_attn   = (const float*)d_in[7];
    const float* w1       = (const float*)d_in[8];
    const float* b1       = (const float*)d_in[9];
    const float* w2       = (const float*)d_in[10];
    const float* b2       = (const float*)d_in[11];
    float* out = (float*)d_out;

    float* ws   = (float*)d_ws;
    float* hs   = ws;
    float* h_st = hs + (size_t)Bn * Tn * Hn;
    float* c_st = h_st + (size_t)Bn * Hn;
    float* pre  = c_st + (size_t)Bn * Hn;

    int tch = 512;
    while (tch > 16) {
        size_t need = ((size_t)Bn * Tn * Hn + 2 * (size_t)Bn * Hn +
                       (size_t)Bn * tch * Gn) * sizeof(float);
        if (need <= ws_size) break;
        tch >>= 1;
    }
    int tlog = 31 - __builtin_clz((unsigned)tch);

    for (int l = 0; l < Ln; l++) {
        const float* A = (l == 0) ? x : hs;
        int K = (l == 0) ? Dn : Hn;
        const float* W = (l == 0) ? w_ih0 : (w_ih_rest + (size_t)(l - 1) * Gn * Hn);
        const float* whl = w_hh + (size_t)l * Gn * Hn;
        for (int c = 0; c < Tn / tch; c++) {
            dim3 gg(tch, 4);
            gemm_pre<<<gg, 256, 0, stream>>>(A, K, Tn * K, c * tch, tlog,
                                             W, b_ih + l * Gn, b_hh + l * Gn, pre);
            lstm_scan<<<Bn, 512, 0, stream>>>(pre, whl, hs, h_st, c_st,
                                              c * tch, tch, c == 0 ? 1 : 0);
        }
    }
    head_kernel<<<Bn, 256, 0, stream>>>(hs, w_attn, b_attn, w1, b1, w2, b2, out);
}